// Round 13
// baseline (291.025 us; speedup 1.0000x reference)
//
#include <hip/hip_runtime.h>
#include <hip/hip_fp16.h>

// GCN 2-layer: out = (Â relu(Â (x@W1) + b1)) @ W2 + b2,  Â = D^-1/2 (A+I) D^-1/2
// N=100000, E=3200000, dims 128 -> 32 -> 16, fp32 in/out.
// Round 15: REVERT partition to the r9-r11 register-staged single-pass form.
// r14 exposed partition_edges as top dispatch (59.4us, VALUBusy 3.4%,
// occupancy 27.7%): the r13 two-pass 16K/1024thr form has only 196 WGs for
// 256 CUs -> latency-bound underparallelism. Reg-staged 256thr/4096-edge
// tiles give 782 WGs (3.05/CU), 16 independent edge loads in flight per
// thread, one barrier pair. Write runs shorten to ~21B -- irrelevant at 15%
// of write BW. Everything else byte-identical to r14 (278.2us best):
// de-barriered agg1 (per-wave sW2, lgkmcnt), byte-offset gathers, LDS
// build_rows, reg-blocked fp16 gemm1, zero pad row at N.

#define IN_DIM 128
#define HID1 32
#define HID2 16

#define BSHIFT 7                 // 128 nodes per bucket
#define MAXNB 1024               // supports N <= 131072 (src < 2^17 packing)
#define SLABCAP 4736             // slab capacity per bucket (mean 4096 + 10 sigma)
#define P2_TILE 4096             // edges per workgroup in partition pass
#define P2_PER_THREAD 16

__device__ __forceinline__ void load_edge(const int* __restrict__ e32, int is64,
                                          long e, long E, int& s, int& d) {
    if (is64) { s = e32[2 * e];  d = e32[2 * E + 2 * e]; }
    else      { s = e32[e];      d = e32[E + e]; }
}

__device__ __forceinline__ void h8acc(float4& acc, uint2 u) {
    __half2 a = *(__half2*)&u.x, b = *(__half2*)&u.y;
    float2 fa = __half22float2(a), fb = __half22float2(b);
    acc.x += fa.x; acc.y += fa.y; acc.z += fb.x; acc.w += fb.y;
}

// ---------------------------------------------------------------------------
// init cursors + total + edge dtype probe
__global__ void init_cursors(const int* __restrict__ e32, int* __restrict__ flag,
                             int* __restrict__ total,
                             int* __restrict__ bucketCursor, int NB) {
    int i = blockIdx.x * blockDim.x + threadIdx.x;
    if (i < NB) bucketCursor[i] = i * SLABCAP;
    if (blockIdx.x == 0 && threadIdx.x == 0) {
        *total = 0;
        int is64 = 1;
        for (int k = 0; k < 64; ++k)
            if (e32[2 * k + 1] != 0) { is64 = 0; break; }
        *flag = is64;
    }
}

// Partition edges into per-bucket slabs as packed u32 (src | dstLocal<<17).
// Register-staged single pass: 16 edges/thread issued independently, LDS
// histogram, chunk reservation, contiguous-run writes. 782 WGs (3/CU).
__global__ __launch_bounds__(256) void partition_edges(const int* __restrict__ e32,
                                                       const int* __restrict__ flag,
                                                       int* __restrict__ bucketCursor,
                                                       unsigned int* __restrict__ part,
                                                       int E, int NB) {
    __shared__ int lbase[MAXNB];   // histogram, then global-base cursor
    for (int i = threadIdx.x; i < NB; i += 256) lbase[i] = 0;
    __syncthreads();
    int is64 = *flag;
    long e0 = (long)blockIdx.x * P2_TILE;
    unsigned int v[P2_PER_THREAD];
    int bb[P2_PER_THREAD];
#pragma unroll
    for (int i = 0; i < P2_PER_THREAD; ++i) {
        long e = e0 + threadIdx.x + i * 256;
        if (e < E) {
            int s, d;
            load_edge(e32, is64, e, E, s, d);
            bb[i] = d >> BSHIFT;
            v[i] = (unsigned int)s | ((unsigned int)(d & ((1 << BSHIFT) - 1)) << 17);
            atomicAdd(&lbase[bb[i]], 1);
        } else {
            bb[i] = -1;
        }
    }
    __syncthreads();
    // reserve one contiguous chunk per non-empty bucket (cursor at slab base)
    for (int i = threadIdx.x; i < NB; i += 256) {
        int c = lbase[i];
        lbase[i] = c ? atomicAdd(&bucketCursor[i], c) : 0;
    }
    __syncthreads();
#pragma unroll
    for (int i = 0; i < P2_PER_THREAD; ++i) {
        if (bb[i] >= 0) {
            int pos = atomicAdd(&lbase[bb[i]], 1);
            if (pos < (bb[i] + 1) * SLABCAP)   // overflow guard (P ~ 1e-20)
                part[pos] = v[i];
        }
    }
}

// P3: one WG (256 thr) per 128-node bucket. Slab staged in LDS once; count,
// scan (128 wide), scatter srcs into a region allocated by one global
// atomicAdd. Emits rowStart/cnt/inv.
__global__ __launch_bounds__(256) void build_rows(const unsigned int* __restrict__ part,
                                                  const int* __restrict__ bucketCursor,
                                                  int* __restrict__ total,
                                                  int* __restrict__ rowStart,
                                                  int* __restrict__ cnt,
                                                  float* __restrict__ inv,
                                                  int* __restrict__ srcs, int N) {
    __shared__ unsigned int sSlab[SLABCAP];   // 18.5 KB
    __shared__ int lc[128];
    __shared__ int lofs[128];
    __shared__ int wsum[2];
    __shared__ int sGbase;
    int b = blockIdx.x;
    int sbeg = b * SLABCAP;
    int size = bucketCursor[b] - sbeg;
    if (size > SLABCAP) size = SLABCAP;
    int tid = threadIdx.x;
    if (tid < 128) lc[tid] = 0;
    __syncthreads();
    for (int i = tid; i < size; i += 256) {      // single global read of slab
        unsigned int v = part[sbeg + i];
        sSlab[i] = v;
        atomicAdd(&lc[v >> 17], 1);
    }
    if (tid == 0) sGbase = atomicAdd(total, size);   // region alloc (any order)
    __syncthreads();
    if (tid < 128) {
        int gbase = sGbase;
        int c = lc[tid];
        int s = c;
#pragma unroll
        for (int off = 1; off < 64; off <<= 1) {
            int t = __shfl_up(s, off, 64);
            if ((tid & 63) >= off) s += t;
        }
        if ((tid & 63) == 63) wsum[tid >> 6] = s;
        __syncthreads();
        int wb = (tid >= 64) ? wsum[0] : 0;
        int gstart = gbase + wb + s - c;   // exclusive scan + region base
        int n = (b << BSHIFT) + tid;
        if (n < N) {
            rowStart[n] = gstart;
            cnt[n] = c;
            inv[n] = rsqrtf((float)(c + 1));
        }
        lofs[tid] = gstart;
    } else {
        __syncthreads();
    }
    __syncthreads();
    for (int i = tid; i < size; i += 256) {
        unsigned int v = sSlab[i];
        int pos = atomicAdd(&lofs[v >> 17], 1);
        srcs[pos] = (int)(v & 0x1FFFF);
    }
}

// ---------------------------------------------------------------------------
// xwh = fp16( (x @ W1) * inv[row] ), rows 0..N inclusive (row N = zero pad).
// Block 256 threads = 128 rows; thread computes 4 rows x 4 cols fp32, stores
// fp16 pairs (uint2 = 4 halves). W1 in LDS as float4.
__global__ __launch_bounds__(256) void gemm1(const float* __restrict__ x,
                                             const float* __restrict__ W1,
                                             const float* __restrict__ inv,
                                             __half* __restrict__ xwh, int N) {
    __shared__ float4 sW4[IN_DIM * 8];   // 16 KB  (W1 as [128][8] float4)
    for (int i = threadIdx.x; i < IN_DIM * 8; i += 256)
        sW4[i] = ((const float4*)W1)[i];
    __syncthreads();

    int rq = threadIdx.x >> 3;           // 0..31 -> 4-row group
    int cq = threadIdx.x & 7;            // col quad (4 cols)
    int r0 = blockIdx.x * 128 + rq * 4;
    const float4* x4 = (const float4*)x; // x as [N][32] float4
    const float4 z4 = make_float4(0.f, 0.f, 0.f, 0.f);

    float4 acc[4];
#pragma unroll
    for (int i = 0; i < 4; ++i) acc[i] = z4;

    for (int k4 = 0; k4 < IN_DIM / 4; ++k4) {   // 32 iterations
        float4 xa[4];
#pragma unroll
        for (int i = 0; i < 4; ++i) {
            int r = r0 + i;
            xa[i] = (r < N) ? x4[(size_t)r * 32 + k4] : z4;
        }
#pragma unroll
        for (int kk = 0; kk < 4; ++kk) {
            float4 w = sW4[(k4 * 4 + kk) * 8 + cq];
#pragma unroll
            for (int i = 0; i < 4; ++i) {
                float xs = (kk == 0) ? xa[i].x : (kk == 1) ? xa[i].y
                         : (kk == 2) ? xa[i].z : xa[i].w;
                acc[i].x += xs * w.x;
                acc[i].y += xs * w.y;
                acc[i].z += xs * w.z;
                acc[i].w += xs * w.w;
            }
        }
    }

#pragma unroll
    for (int i = 0; i < 4; ++i) {
        int r = r0 + i;
        if (r <= N) {                         // row N: acc==0, scale 0
            float sc = (r < N) ? inv[r] : 0.f;
            __half2 p0 = __floats2half2_rn(acc[i].x * sc, acc[i].y * sc);
            __half2 p1 = __floats2half2_rn(acc[i].z * sc, acc[i].w * sc);
            uint2 u;
            u.x = *(unsigned int*)&p0;
            u.y = *(unsigned int*)&p1;
            ((uint2*)xwh)[(size_t)r * 8 + cq] = u;
        }
    }
}

// ---------------------------------------------------------------------------
// Layer-1 aggregate + fused gemm2: one 64-lane wave per node, BARRIER-FREE.
// lane = eg*8 + r: edge slot eg (0..7), channel quad r (0..7, 4 halves=8B).
// sW2 duplicated per wave; sAgg per-wave -> all LDS traffic wave-local, so
// the block barrier is replaced by s_waitcnt lgkmcnt(0). srcs preloads are
// pre-scaled to byte offsets (sv<<6). Phase-split vals[8]; zero row at N.
__global__ __launch_bounds__(256) void agg1_k(const int* __restrict__ rowStart,
                                              const int* __restrict__ cnt,
                                              const int* __restrict__ srcs,
                                              const float* __restrict__ inv,
                                              const __half* __restrict__ xwh,
                                              const float* __restrict__ b1,
                                              const float* __restrict__ W2,
                                              __half* __restrict__ hwh, int N) {
    __shared__ float sW2[4][HID1 * HID2];   // per-wave copies, 8 KB
    __shared__ float sAgg[4][HID1];         // per-wave, 512 B

    int w    = threadIdx.x >> 6;         // wave in block
    int lane = threadIdx.x & 63;
    // per-wave W2 copy (wave-local LDS only)
    for (int i = lane; i < HID1 * HID2 / 4; i += 64)
        ((float4*)sW2[w])[i] = ((const float4*)W2)[i];

    int node = blockIdx.x * 4 + w;
    int nr   = (node < N) ? node : 0;    // safe read index
    int start = rowStart[nr];
    int len   = (node < N) ? cnt[nr] : 0;
    float invn = (node < N) ? inv[nr] : 0.f;   // node==N pad -> 0 output
    int eg = lane >> 3;                  // edge slot
    int r  = lane & 7;                   // channel quad
    const char* base = (const char*)xwh;
    int roff = r * 8;

    int svb = ((lane < len) ? srcs[start + lane] : N) << 6;  // row BYTE offset
    uint2 selfv = *(const uint2*)(base + ((size_t)nr << 6) + roff);

    // phase 1: issue all group gathers (static indices -> registers)
    uint2 vals[8];
#pragma unroll
    for (int g = 0; g < 8; ++g) {
        int jb = g * 8;
        if (jb < len) {                                  // wave-uniform branch
            int off = __shfl(svb, jb + eg, 64);          // pad slots -> row N
            vals[g] = *(const uint2*)(base + off + roff);
        }
    }
    // phase 2: accumulate
    float4 acc = make_float4(0.f, 0.f, 0.f, 0.f);
    if (eg == 0) h8acc(acc, selfv);
#pragma unroll
    for (int g = 0; g < 8; ++g)
        if (g * 8 < len) h8acc(acc, vals[g]);

    for (int j = 64 + eg; j < len; j += 8)               // ultra-rare tail
        h8acc(acc, *(const uint2*)(base + ((size_t)srcs[start + j] << 6) + roff));

#pragma unroll
    for (int off = 32; off >= 8; off >>= 1) {            // reduce over eg
        acc.x += __shfl_down(acc.x, off, 64);
        acc.y += __shfl_down(acc.y, off, 64);
        acc.z += __shfl_down(acc.z, off, 64);
        acc.w += __shfl_down(acc.w, off, 64);
    }
    if (lane < 8) {                                      // lanes 0..7: r=lane
        float4 bb = ((const float4*)b1)[lane];
        float4 o;
        o.x = fmaxf(bb.x + invn * acc.x, 0.f);
        o.y = fmaxf(bb.y + invn * acc.y, 0.f);
        o.z = fmaxf(bb.z + invn * acc.z, 0.f);
        o.w = fmaxf(bb.w + invn * acc.w, 0.f);
        ((float4*)&sAgg[w][0])[lane] = o;
    }
    // wave-local LDS RAW: wait for this wave's ds_writes, no block barrier
    asm volatile("s_waitcnt lgkmcnt(0)" ::: "memory");

    // fused gemm2: 16 lanes per wave, y[o] = sum_c sAgg[w][c] * W2[c][o]
    if (lane < HID2 && node <= N) {
        float y = 0.f;
#pragma unroll
        for (int cc = 0; cc < HID1; ++cc)
            y += sAgg[w][cc] * sW2[w][cc * HID2 + lane];
        hwh[(size_t)node * HID2 + lane] = __float2half_rn(y * invn);  // row N = 0
    }
}

// Layer-2 aggregate: lane = eg*4 + q: edge slot eg (0..15), channel quad q
// (4 halves = 8 B). Byte-offset preload (sv<<5); phase-split vals[4].
__global__ __launch_bounds__(256) void agg2_k(const int* __restrict__ rowStart,
                                              const int* __restrict__ cnt,
                                              const int* __restrict__ srcs,
                                              const float* __restrict__ inv,
                                              const __half* __restrict__ hwh,
                                              const float* __restrict__ b2,
                                              float* __restrict__ out, int N) {
    int wave = (blockIdx.x * blockDim.x + threadIdx.x) >> 6;
    int lane = threadIdx.x & 63;
    if (wave >= N) return;
    int n = wave;
    int eg = lane >> 2;            // 0..15
    int q  = lane & 3;             // channel quad
    int start = rowStart[n];
    int len   = cnt[n];
    float invn = inv[n];
    const char* base = (const char*)hwh;
    int roff = q * 8;

    int svb = ((lane < len) ? srcs[start + lane] : N) << 5;  // row BYTE offset
    uint2 selfv = *(const uint2*)(base + ((size_t)n << 5) + roff);

    uint2 vals[4];
#pragma unroll
    for (int g = 0; g < 4; ++g) {
        int jb = g * 16;
        if (jb < len) {
            int off = __shfl(svb, jb + eg, 64);
            vals[g] = *(const uint2*)(base + off + roff);
        }
    }
    float4 acc = make_float4(0.f, 0.f, 0.f, 0.f);
    if (eg == 0) h8acc(acc, selfv);
#pragma unroll
    for (int g = 0; g < 4; ++g)
        if (g * 16 < len) h8acc(acc, vals[g]);

    for (int j = 64 + eg; j < len; j += 16)              // ultra-rare tail
        h8acc(acc, *(const uint2*)(base + ((size_t)srcs[start + j] << 5) + roff));

#pragma unroll
    for (int off = 32; off >= 4; off >>= 1) {            // reduce over eg
        acc.x += __shfl_down(acc.x, off, 64);
        acc.y += __shfl_down(acc.y, off, 64);
        acc.z += __shfl_down(acc.z, off, 64);
        acc.w += __shfl_down(acc.w, off, 64);
    }
    if (lane < 4) {                                      // lanes 0..3: q=lane
        float4 bb = ((const float4*)b2)[lane];
        float4 o;
        o.x = bb.x + invn * acc.x;
        o.y = bb.y + invn * acc.y;
        o.z = bb.z + invn * acc.z;
        o.w = bb.w + invn * acc.w;
        ((float4*)out)[(size_t)n * 4 + lane] = o;
    }
}

// ---------------------------------------------------------------------------
extern "C" void kernel_launch(void* const* d_in, const int* in_sizes, int n_in,
                              void* d_out, int out_size, void* d_ws, size_t ws_size,
                              hipStream_t stream) {
    const float* x  = (const float*)d_in[0];
    const float* W1 = (const float*)d_in[1];
    const float* b1 = (const float*)d_in[2];
    const float* W2 = (const float*)d_in[3];
    const float* b2 = (const float*)d_in[4];
    const int*  e32 = (const int*)d_in[5];
    float* out = (float*)d_out;

    const int N = in_sizes[0] / IN_DIM;   // 100000
    const int E = in_sizes[5] / 2;        // 3200000
    const int Npad = ((N + 63) / 64) * 64;
    const int Epad = ((E + 63) / 64) * 64;
    const int NB   = (N + (1 << BSHIFT) - 1) >> BSHIFT;   // 782 buckets of 128

    // workspace layout (byte-based)
    char* ws = (char*)d_ws;
    int*   flag         = (int*)ws;                       // 1
    int*   total        = (int*)(ws + 64);                // 1
    int*   bucketCursor = (int*)(ws + 256);               // NB (<=1024)
    int*   cnt      = bucketCursor + 1088;                // N
    int*   rowStart = cnt + Npad;                         // N
    float* inv      = (float*)(rowStart + Npad);          // N
    int*   srcs     = (int*)(inv + Npad);                 // E
    // part (NB*SLABCAP u32 = 14.1MB) aliases xwh ((N+1)*32 halves = 6.4MB):
    // part dead before gemm1 writes xwh. hwh after the part region.
    size_t slabBytes = (size_t)NB * SLABCAP * 4;
    unsigned int* part = (unsigned int*)(srcs + Epad);
    __half* xwh = (__half*)part;
    __half* hwh = (__half*)((char*)part + slabBytes);     // (N+1)*16 halves

    init_cursors<<<(NB + 255) / 256, 256, 0, stream>>>(e32, flag, total,
                                                       bucketCursor, NB);
    partition_edges<<<(E + P2_TILE - 1) / P2_TILE, 256, 0, stream>>>(
        e32, flag, bucketCursor, part, E, NB);
    build_rows<<<NB, 256, 0, stream>>>(part, bucketCursor, total,
                                       rowStart, cnt, inv, srcs, N);

    gemm1<<<(N + 1 + 127) / 128, 256, 0, stream>>>(x, W1, inv, xwh, N);
    agg1_k<<<(N + 1 + 3) / 4, 256, 0, stream>>>(rowStart, cnt, srcs, inv, xwh,
                                                b1, W2, hwh, N);
    agg2_k<<<(N + 3) / 4, 256, 0, stream>>>(rowStart, cnt, srcs, inv, hwh,
                                            b2, out, N);
}

// Round 14
// 266.307 us; speedup vs baseline: 1.0928x; 1.0928x over previous
//
#include <hip/hip_runtime.h>
#include <hip/hip_fp16.h>

// GCN 2-layer: out = (Â relu(Â (x@W1) + b1)) @ W2 + b2,  Â = D^-1/2 (A+I) D^-1/2
// N=100000, E=3200000, dims 128 -> 32 -> 16, fp32 in/out.
// Round 16: restore r14 (278.2us verified best; r15's reg-staged partition
// regressed 13us -> two-pass big-tile partition wins: 4x longer write runs +
// 4x fewer reservation atomics beat occupancy). One isolated change:
// agg2 packs 2 NODES PER WAVE (half-wave per node: eg 0..7 x q 0..3):
// 50K waves instead of 100K, gather instrs halved, per-wave fixed overhead
// (srcs preload, reduce, meta) amortized over 2 nodes. Group branch made
// wave-uniform via lenmax=max(len, shfl_xor(len,32)); short half gathers the
// zero pad row (correct by construction, shfl stays exec-uniform).
// Frozen from r14: two-pass 16K/1024 partition (BSHIFT=7), LDS build_rows,
// reg-blocked fp16 gemm1, de-barriered agg1 (per-wave sW2, byte offsets).

#define IN_DIM 128
#define HID1 32
#define HID2 16

#define BSHIFT 7                 // 128 nodes per bucket
#define MAXNB 1024               // supports N <= 131072 (src < 2^17 packing)
#define SLABCAP 4736             // slab capacity per bucket (mean 4096 + 10 sigma)
#define P2T 16384                // edges per workgroup in partition pass

__device__ __forceinline__ void load_edge(const int* __restrict__ e32, int is64,
                                          long e, long E, int& s, int& d) {
    if (is64) { s = e32[2 * e];  d = e32[2 * E + 2 * e]; }
    else      { s = e32[e];      d = e32[E + e]; }
}

__device__ __forceinline__ void h8acc(float4& acc, uint2 u) {
    __half2 a = *(__half2*)&u.x, b = *(__half2*)&u.y;
    float2 fa = __half22float2(a), fb = __half22float2(b);
    acc.x += fa.x; acc.y += fa.y; acc.z += fb.x; acc.w += fb.y;
}

// ---------------------------------------------------------------------------
// init cursors + total + edge dtype probe
__global__ void init_cursors(const int* __restrict__ e32, int* __restrict__ flag,
                             int* __restrict__ total,
                             int* __restrict__ bucketCursor, int NB) {
    int i = blockIdx.x * blockDim.x + threadIdx.x;
    if (i < NB) bucketCursor[i] = i * SLABCAP;
    if (blockIdx.x == 0 && threadIdx.x == 0) {
        *total = 0;
        int is64 = 1;
        for (int k = 0; k < 64; ++k)
            if (e32[2 * k + 1] != 0) { is64 = 0; break; }
        *flag = is64;
    }
}

// Partition edges into per-bucket slabs as packed u32 (src | dstLocal<<17).
// Two passes over a 16K-edge tile: A) LDS histogram from the dst stream,
// reserve one chunk per bucket; B) re-read (L2-hot) and place.
__global__ __launch_bounds__(1024) void partition_edges(const int* __restrict__ e32,
                                                        const int* __restrict__ flag,
                                                        int* __restrict__ bucketCursor,
                                                        unsigned int* __restrict__ part,
                                                        int E, int NB) {
    __shared__ int lbase[MAXNB];   // histogram, then global cursor per bucket
    for (int i = threadIdx.x; i < NB; i += 1024) lbase[i] = 0;
    __syncthreads();
    int is64 = *flag;
    long e0 = (long)blockIdx.x * P2T;
    long eend = e0 + P2T; if (eend > E) eend = E;
    // pass A: histogram over dst
    for (long e = e0 + threadIdx.x; e < eend; e += 1024) {
        int d = is64 ? e32[2 * E + 2 * e] : e32[E + e];
        atomicAdd(&lbase[d >> BSHIFT], 1);
    }
    __syncthreads();
    // reserve one contiguous chunk per non-empty bucket
    for (int b = threadIdx.x; b < NB; b += 1024) {
        int c = lbase[b];
        lbase[b] = c ? atomicAdd(&bucketCursor[b], c) : 0;
    }
    __syncthreads();
    // pass B: place (dst stream L2-hot from pass A)
    for (long e = e0 + threadIdx.x; e < eend; e += 1024) {
        int s, d;
        load_edge(e32, is64, e, E, s, d);
        int bkt = d >> BSHIFT;
        int pos = atomicAdd(&lbase[bkt], 1);
        if (pos < (bkt + 1) * SLABCAP)   // overflow guard (P ~ 1e-20)
            part[pos] = (unsigned int)s |
                        ((unsigned int)(d & ((1 << BSHIFT) - 1)) << 17);
    }
}

// P3: one WG (256 thr) per 128-node bucket. Slab staged in LDS once; count,
// scan (128 wide), scatter srcs into a region allocated by one global
// atomicAdd. Emits rowStart/cnt/inv.
__global__ __launch_bounds__(256) void build_rows(const unsigned int* __restrict__ part,
                                                  const int* __restrict__ bucketCursor,
                                                  int* __restrict__ total,
                                                  int* __restrict__ rowStart,
                                                  int* __restrict__ cnt,
                                                  float* __restrict__ inv,
                                                  int* __restrict__ srcs, int N) {
    __shared__ unsigned int sSlab[SLABCAP];   // 18.5 KB
    __shared__ int lc[128];
    __shared__ int lofs[128];
    __shared__ int wsum[2];
    __shared__ int sGbase;
    int b = blockIdx.x;
    int sbeg = b * SLABCAP;
    int size = bucketCursor[b] - sbeg;
    if (size > SLABCAP) size = SLABCAP;
    int tid = threadIdx.x;
    if (tid < 128) lc[tid] = 0;
    __syncthreads();
    for (int i = tid; i < size; i += 256) {      // single global read of slab
        unsigned int v = part[sbeg + i];
        sSlab[i] = v;
        atomicAdd(&lc[v >> 17], 1);
    }
    if (tid == 0) sGbase = atomicAdd(total, size);   // region alloc (any order)
    __syncthreads();
    if (tid < 128) {
        int gbase = sGbase;
        int c = lc[tid];
        int s = c;
#pragma unroll
        for (int off = 1; off < 64; off <<= 1) {
            int t = __shfl_up(s, off, 64);
            if ((tid & 63) >= off) s += t;
        }
        if ((tid & 63) == 63) wsum[tid >> 6] = s;
        __syncthreads();
        int wb = (tid >= 64) ? wsum[0] : 0;
        int gstart = gbase + wb + s - c;   // exclusive scan + region base
        int n = (b << BSHIFT) + tid;
        if (n < N) {
            rowStart[n] = gstart;
            cnt[n] = c;
            inv[n] = rsqrtf((float)(c + 1));
        }
        lofs[tid] = gstart;
    } else {
        __syncthreads();
    }
    __syncthreads();
    for (int i = tid; i < size; i += 256) {
        unsigned int v = sSlab[i];
        int pos = atomicAdd(&lofs[v >> 17], 1);
        srcs[pos] = (int)(v & 0x1FFFF);
    }
}

// ---------------------------------------------------------------------------
// xwh = fp16( (x @ W1) * inv[row] ), rows 0..N inclusive (row N = zero pad).
// Block 256 threads = 128 rows; thread computes 4 rows x 4 cols fp32, stores
// fp16 pairs (uint2 = 4 halves). W1 in LDS as float4.
__global__ __launch_bounds__(256) void gemm1(const float* __restrict__ x,
                                             const float* __restrict__ W1,
                                             const float* __restrict__ inv,
                                             __half* __restrict__ xwh, int N) {
    __shared__ float4 sW4[IN_DIM * 8];   // 16 KB  (W1 as [128][8] float4)
    for (int i = threadIdx.x; i < IN_DIM * 8; i += 256)
        sW4[i] = ((const float4*)W1)[i];
    __syncthreads();

    int rq = threadIdx.x >> 3;           // 0..31 -> 4-row group
    int cq = threadIdx.x & 7;            // col quad (4 cols)
    int r0 = blockIdx.x * 128 + rq * 4;
    const float4* x4 = (const float4*)x; // x as [N][32] float4
    const float4 z4 = make_float4(0.f, 0.f, 0.f, 0.f);

    float4 acc[4];
#pragma unroll
    for (int i = 0; i < 4; ++i) acc[i] = z4;

    for (int k4 = 0; k4 < IN_DIM / 4; ++k4) {   // 32 iterations
        float4 xa[4];
#pragma unroll
        for (int i = 0; i < 4; ++i) {
            int r = r0 + i;
            xa[i] = (r < N) ? x4[(size_t)r * 32 + k4] : z4;
        }
#pragma unroll
        for (int kk = 0; kk < 4; ++kk) {
            float4 w = sW4[(k4 * 4 + kk) * 8 + cq];
#pragma unroll
            for (int i = 0; i < 4; ++i) {
                float xs = (kk == 0) ? xa[i].x : (kk == 1) ? xa[i].y
                         : (kk == 2) ? xa[i].z : xa[i].w;
                acc[i].x += xs * w.x;
                acc[i].y += xs * w.y;
                acc[i].z += xs * w.z;
                acc[i].w += xs * w.w;
            }
        }
    }

#pragma unroll
    for (int i = 0; i < 4; ++i) {
        int r = r0 + i;
        if (r <= N) {                         // row N: acc==0, scale 0
            float sc = (r < N) ? inv[r] : 0.f;
            __half2 p0 = __floats2half2_rn(acc[i].x * sc, acc[i].y * sc);
            __half2 p1 = __floats2half2_rn(acc[i].z * sc, acc[i].w * sc);
            uint2 u;
            u.x = *(unsigned int*)&p0;
            u.y = *(unsigned int*)&p1;
            ((uint2*)xwh)[(size_t)r * 8 + cq] = u;
        }
    }
}

// ---------------------------------------------------------------------------
// Layer-1 aggregate + fused gemm2: one 64-lane wave per node, BARRIER-FREE.
// lane = eg*8 + r: edge slot eg (0..7), channel quad r (0..7, 4 halves=8B).
// sW2 duplicated per wave; sAgg per-wave -> all LDS traffic wave-local, so
// the block barrier is replaced by s_waitcnt lgkmcnt(0). srcs preloads are
// pre-scaled to byte offsets (sv<<6). Phase-split vals[8]; zero row at N.
__global__ __launch_bounds__(256) void agg1_k(const int* __restrict__ rowStart,
                                              const int* __restrict__ cnt,
                                              const int* __restrict__ srcs,
                                              const float* __restrict__ inv,
                                              const __half* __restrict__ xwh,
                                              const float* __restrict__ b1,
                                              const float* __restrict__ W2,
                                              __half* __restrict__ hwh, int N) {
    __shared__ float sW2[4][HID1 * HID2];   // per-wave copies, 8 KB
    __shared__ float sAgg[4][HID1];         // per-wave, 512 B

    int w    = threadIdx.x >> 6;         // wave in block
    int lane = threadIdx.x & 63;
    // per-wave W2 copy (wave-local LDS only)
    for (int i = lane; i < HID1 * HID2 / 4; i += 64)
        ((float4*)sW2[w])[i] = ((const float4*)W2)[i];

    int node = blockIdx.x * 4 + w;
    int nr   = (node < N) ? node : 0;    // safe read index
    int start = rowStart[nr];
    int len   = (node < N) ? cnt[nr] : 0;
    float invn = (node < N) ? inv[nr] : 0.f;   // node==N pad -> 0 output
    int eg = lane >> 3;                  // edge slot
    int r  = lane & 7;                   // channel quad
    const char* base = (const char*)xwh;
    int roff = r * 8;

    int svb = ((lane < len) ? srcs[start + lane] : N) << 6;  // row BYTE offset
    uint2 selfv = *(const uint2*)(base + ((size_t)nr << 6) + roff);

    // phase 1: issue all group gathers (static indices -> registers)
    uint2 vals[8];
#pragma unroll
    for (int g = 0; g < 8; ++g) {
        int jb = g * 8;
        if (jb < len) {                                  // wave-uniform branch
            int off = __shfl(svb, jb + eg, 64);          // pad slots -> row N
            vals[g] = *(const uint2*)(base + off + roff);
        }
    }
    // phase 2: accumulate
    float4 acc = make_float4(0.f, 0.f, 0.f, 0.f);
    if (eg == 0) h8acc(acc, selfv);
#pragma unroll
    for (int g = 0; g < 8; ++g)
        if (g * 8 < len) h8acc(acc, vals[g]);

    for (int j = 64 + eg; j < len; j += 8)               // ultra-rare tail
        h8acc(acc, *(const uint2*)(base + ((size_t)srcs[start + j] << 6) + roff));

#pragma unroll
    for (int off = 32; off >= 8; off >>= 1) {            // reduce over eg
        acc.x += __shfl_down(acc.x, off, 64);
        acc.y += __shfl_down(acc.y, off, 64);
        acc.z += __shfl_down(acc.z, off, 64);
        acc.w += __shfl_down(acc.w, off, 64);
    }
    if (lane < 8) {                                      // lanes 0..7: r=lane
        float4 bb = ((const float4*)b1)[lane];
        float4 o;
        o.x = fmaxf(bb.x + invn * acc.x, 0.f);
        o.y = fmaxf(bb.y + invn * acc.y, 0.f);
        o.z = fmaxf(bb.z + invn * acc.z, 0.f);
        o.w = fmaxf(bb.w + invn * acc.w, 0.f);
        ((float4*)&sAgg[w][0])[lane] = o;
    }
    // wave-local LDS RAW: wait for this wave's ds_writes, no block barrier
    asm volatile("s_waitcnt lgkmcnt(0)" ::: "memory");

    // fused gemm2: 16 lanes per wave, y[o] = sum_c sAgg[w][c] * W2[c][o]
    if (lane < HID2 && node <= N) {
        float y = 0.f;
#pragma unroll
        for (int cc = 0; cc < HID1; ++cc)
            y += sAgg[w][cc] * sW2[w][cc * HID2 + lane];
        hwh[(size_t)node * HID2 + lane] = __float2half_rn(y * invn);  // row N = 0
    }
}

// Layer-2 aggregate: TWO nodes per wave (half-wave each). Within a half:
// eg = edge slot (0..7), q = channel quad (0..3, 8 B). Two preload registers
// cover 64 slots; groups are wave-uniform via lenmax (short half gathers the
// zero pad row). 50K waves; gather instructions halved vs 1-node/wave.
__global__ __launch_bounds__(256) void agg2_k(const int* __restrict__ rowStart,
                                              const int* __restrict__ cnt,
                                              const int* __restrict__ srcs,
                                              const float* __restrict__ inv,
                                              const __half* __restrict__ hwh,
                                              const float* __restrict__ b2,
                                              float* __restrict__ out, int N) {
    int wpair = (blockIdx.x * blockDim.x + threadIdx.x) >> 6;
    if (wpair * 2 >= N) return;
    int lane = threadIdx.x & 63;
    int half = lane >> 5;          // which node of the pair
    int l32  = lane & 31;
    int n    = wpair * 2 + half;
    bool live = (n < N);
    int nr   = live ? n : 0;
    int start = rowStart[nr];
    int len   = live ? cnt[nr] : 0;
    float invn = live ? inv[nr] : 0.f;
    int eg = l32 >> 2;             // edge slot 0..7
    int q  = l32 & 3;              // channel quad
    const char* base = (const char*)hwh;
    int roff = q * 8;

    // preload up to 64 srcs per half as byte offsets (pad -> row N)
    int svbA = ((l32 < len)      ? srcs[start + l32]      : N) << 5;  // slots 0..31
    int svbB = ((l32 + 32 < len) ? srcs[start + 32 + l32] : N) << 5;  // slots 32..63
    uint2 selfv = *(const uint2*)(base + ((size_t)nr << 5) + roff);

    int lenmax = max(len, __shfl_xor(len, 32, 64));      // wave-uniform bound

    uint2 vals[8];
#pragma unroll
    for (int g = 0; g < 8; ++g) {
        int jb = g * 8;
        if (jb < lenmax) {                               // wave-uniform branch
            // slot j = jb + eg; register choice static per g (jb<32 -> A)
            int off = __shfl((jb < 32) ? svbA : svbB,
                             (half << 5) + ((jb + eg) & 31), 64);
            vals[g] = *(const uint2*)(base + off + roff);
        }
    }
    float4 acc = make_float4(0.f, 0.f, 0.f, 0.f);
    if (eg == 0) h8acc(acc, selfv);                      // self term (pad: zero row)
#pragma unroll
    for (int g = 0; g < 8; ++g)
        if (g * 8 < lenmax) h8acc(acc, vals[g]);         // pad slots add zero row

    for (int j = 64 + eg; j < len; j += 8)               // ultra-rare tail
        h8acc(acc, *(const uint2*)(base + ((size_t)srcs[start + j] << 5) + roff));

#pragma unroll
    for (int off = 16; off >= 4; off >>= 1) {            // reduce over eg (in half)
        acc.x += __shfl_down(acc.x, off, 64);
        acc.y += __shfl_down(acc.y, off, 64);
        acc.z += __shfl_down(acc.z, off, 64);
        acc.w += __shfl_down(acc.w, off, 64);
    }
    if (l32 < 4 && live) {                               // q = l32
        float4 bb = ((const float4*)b2)[l32];
        float4 o;
        o.x = bb.x + invn * acc.x;
        o.y = bb.y + invn * acc.y;
        o.z = bb.z + invn * acc.z;
        o.w = bb.w + invn * acc.w;
        ((float4*)out)[(size_t)n * 4 + l32] = o;
    }
}

// ---------------------------------------------------------------------------
extern "C" void kernel_launch(void* const* d_in, const int* in_sizes, int n_in,
                              void* d_out, int out_size, void* d_ws, size_t ws_size,
                              hipStream_t stream) {
    const float* x  = (const float*)d_in[0];
    const float* W1 = (const float*)d_in[1];
    const float* b1 = (const float*)d_in[2];
    const float* W2 = (const float*)d_in[3];
    const float* b2 = (const float*)d_in[4];
    const int*  e32 = (const int*)d_in[5];
    float* out = (float*)d_out;

    const int N = in_sizes[0] / IN_DIM;   // 100000
    const int E = in_sizes[5] / 2;        // 3200000
    const int Npad = ((N + 63) / 64) * 64;
    const int Epad = ((E + 63) / 64) * 64;
    const int NB   = (N + (1 << BSHIFT) - 1) >> BSHIFT;   // 782 buckets of 128

    // workspace layout (byte-based)
    char* ws = (char*)d_ws;
    int*   flag         = (int*)ws;                       // 1
    int*   total        = (int*)(ws + 64);                // 1
    int*   bucketCursor = (int*)(ws + 256);               // NB (<=1024)
    int*   cnt      = bucketCursor + 1088;                // N
    int*   rowStart = cnt + Npad;                         // N
    float* inv      = (float*)(rowStart + Npad);          // N
    int*   srcs     = (int*)(inv + Npad);                 // E
    // part (NB*SLABCAP u32 = 14.1MB) aliases xwh ((N+1)*32 halves = 6.4MB):
    // part dead before gemm1 writes xwh. hwh after the part region.
    size_t slabBytes = (size_t)NB * SLABCAP * 4;
    unsigned int* part = (unsigned int*)(srcs + Epad);
    __half* xwh = (__half*)part;
    __half* hwh = (__half*)((char*)part + slabBytes);     // (N+1)*16 halves

    init_cursors<<<(NB + 255) / 256, 256, 0, stream>>>(e32, flag, total,
                                                       bucketCursor, NB);
    partition_edges<<<(E + P2T - 1) / P2T, 1024, 0, stream>>>(
        e32, flag, bucketCursor, part, E, NB);
    build_rows<<<NB, 256, 0, stream>>>(part, bucketCursor, total,
                                       rowStart, cnt, inv, srcs, N);

    gemm1<<<(N + 1 + 127) / 128, 256, 0, stream>>>(x, W1, inv, xwh, N);
    agg1_k<<<(N + 1 + 3) / 4, 256, 0, stream>>>(rowStart, cnt, srcs, inv, xwh,
                                                b1, W2, hwh, N);
    int pairs = (N + 1) / 2;   // 2 nodes per wave
    agg2_k<<<(pairs + 3) / 4, 256, 0, stream>>>(rowStart, cnt, srcs, inv, hwh,
                                                b2, out, N);
}

// Round 15
// 265.687 us; speedup vs baseline: 1.0954x; 1.0023x over previous
//
#include <hip/hip_runtime.h>
#include <hip/hip_fp16.h>

// GCN 2-layer: out = (Â relu(Â (x@W1) + b1)) @ W2 + b2,  Â = D^-1/2 (A+I) D^-1/2
// N=100000, E=3200000, dims 128 -> 32 -> 16, fp32 in/out.
// Round 17: reg-staged BIG-TILE partition. r14/r15 disambiguated: r15's
// regression was tile shrink (21B runs, 4x reservations), not reg-staging.
// This round keeps r14 geometry (P2T=16K, 1024 thr, 196 WGs, 84B runs,
// 153K reservations) and adds r15's load batching: v[16]/bb[16] unrolled ->
// 16 independent edge loads in flight before any LDS atomic (r14's loop had
// a dependent atomic after every load -> VALUBusy 3.4%). Pass-B edge re-read
// eliminated (s,d loaded once). Everything else byte-identical to r16
// (266.3us best): LDS build_rows, reg-blocked fp16 gemm1, de-barriered agg1,
// 2-node/wave agg2.

#define IN_DIM 128
#define HID1 32
#define HID2 16

#define BSHIFT 7                 // 128 nodes per bucket
#define MAXNB 1024               // supports N <= 131072 (src < 2^17 packing)
#define SLABCAP 4736             // slab capacity per bucket (mean 4096 + 10 sigma)
#define P2T 16384                // edges per workgroup in partition pass
#define P2_PER_THREAD 16         // 16 edges x 1024 threads = 16384

__device__ __forceinline__ void load_edge(const int* __restrict__ e32, int is64,
                                          long e, long E, int& s, int& d) {
    if (is64) { s = e32[2 * e];  d = e32[2 * E + 2 * e]; }
    else      { s = e32[e];      d = e32[E + e]; }
}

__device__ __forceinline__ void h8acc(float4& acc, uint2 u) {
    __half2 a = *(__half2*)&u.x, b = *(__half2*)&u.y;
    float2 fa = __half22float2(a), fb = __half22float2(b);
    acc.x += fa.x; acc.y += fa.y; acc.z += fb.x; acc.w += fb.y;
}

// ---------------------------------------------------------------------------
// init cursors + total + edge dtype probe
__global__ void init_cursors(const int* __restrict__ e32, int* __restrict__ flag,
                             int* __restrict__ total,
                             int* __restrict__ bucketCursor, int NB) {
    int i = blockIdx.x * blockDim.x + threadIdx.x;
    if (i < NB) bucketCursor[i] = i * SLABCAP;
    if (blockIdx.x == 0 && threadIdx.x == 0) {
        *total = 0;
        int is64 = 1;
        for (int k = 0; k < 64; ++k)
            if (e32[2 * k + 1] != 0) { is64 = 0; break; }
        *flag = is64;
    }
}

// Partition edges into per-bucket slabs as packed u32 (src | dstLocal<<17).
// Register-staged big tile: 16 edges/thread loaded independently (latency
// batched), LDS histogram, one chunk reservation per bucket, placement.
__global__ __launch_bounds__(1024) void partition_edges(const int* __restrict__ e32,
                                                        const int* __restrict__ flag,
                                                        int* __restrict__ bucketCursor,
                                                        unsigned int* __restrict__ part,
                                                        int E, int NB) {
    __shared__ int lbase[MAXNB];   // histogram, then global-base cursor
    for (int i = threadIdx.x; i < NB; i += 1024) lbase[i] = 0;
    __syncthreads();
    int is64 = *flag;
    long e0 = (long)blockIdx.x * P2T;
    unsigned int v[P2_PER_THREAD];
    int bb[P2_PER_THREAD];
#pragma unroll
    for (int i = 0; i < P2_PER_THREAD; ++i) {
        long e = e0 + threadIdx.x + i * 1024;
        if (e < E) {
            int s, d;
            load_edge(e32, is64, e, E, s, d);
            bb[i] = d >> BSHIFT;
            v[i] = (unsigned int)s | ((unsigned int)(d & ((1 << BSHIFT) - 1)) << 17);
            atomicAdd(&lbase[bb[i]], 1);
        } else {
            bb[i] = -1;
        }
    }
    __syncthreads();
    // reserve one contiguous chunk per non-empty bucket (cursor at slab base)
    for (int b = threadIdx.x; b < NB; b += 1024) {
        int c = lbase[b];
        lbase[b] = c ? atomicAdd(&bucketCursor[b], c) : 0;
    }
    __syncthreads();
#pragma unroll
    for (int i = 0; i < P2_PER_THREAD; ++i) {
        if (bb[i] >= 0) {
            int pos = atomicAdd(&lbase[bb[i]], 1);
            if (pos < (bb[i] + 1) * SLABCAP)   // overflow guard (P ~ 1e-20)
                part[pos] = v[i];
        }
    }
}

// P3: one WG (256 thr) per 128-node bucket. Slab staged in LDS once; count,
// scan (128 wide), scatter srcs into a region allocated by one global
// atomicAdd. Emits rowStart/cnt/inv.
__global__ __launch_bounds__(256) void build_rows(const unsigned int* __restrict__ part,
                                                  const int* __restrict__ bucketCursor,
                                                  int* __restrict__ total,
                                                  int* __restrict__ rowStart,
                                                  int* __restrict__ cnt,
                                                  float* __restrict__ inv,
                                                  int* __restrict__ srcs, int N) {
    __shared__ unsigned int sSlab[SLABCAP];   // 18.5 KB
    __shared__ int lc[128];
    __shared__ int lofs[128];
    __shared__ int wsum[2];
    __shared__ int sGbase;
    int b = blockIdx.x;
    int sbeg = b * SLABCAP;
    int size = bucketCursor[b] - sbeg;
    if (size > SLABCAP) size = SLABCAP;
    int tid = threadIdx.x;
    if (tid < 128) lc[tid] = 0;
    __syncthreads();
    for (int i = tid; i < size; i += 256) {      // single global read of slab
        unsigned int v = part[sbeg + i];
        sSlab[i] = v;
        atomicAdd(&lc[v >> 17], 1);
    }
    if (tid == 0) sGbase = atomicAdd(total, size);   // region alloc (any order)
    __syncthreads();
    if (tid < 128) {
        int gbase = sGbase;
        int c = lc[tid];
        int s = c;
#pragma unroll
        for (int off = 1; off < 64; off <<= 1) {
            int t = __shfl_up(s, off, 64);
            if ((tid & 63) >= off) s += t;
        }
        if ((tid & 63) == 63) wsum[tid >> 6] = s;
        __syncthreads();
        int wb = (tid >= 64) ? wsum[0] : 0;
        int gstart = gbase + wb + s - c;   // exclusive scan + region base
        int n = (b << BSHIFT) + tid;
        if (n < N) {
            rowStart[n] = gstart;
            cnt[n] = c;
            inv[n] = rsqrtf((float)(c + 1));
        }
        lofs[tid] = gstart;
    } else {
        __syncthreads();
    }
    __syncthreads();
    for (int i = tid; i < size; i += 256) {
        unsigned int v = sSlab[i];
        int pos = atomicAdd(&lofs[v >> 17], 1);
        srcs[pos] = (int)(v & 0x1FFFF);
    }
}

// ---------------------------------------------------------------------------
// xwh = fp16( (x @ W1) * inv[row] ), rows 0..N inclusive (row N = zero pad).
// Block 256 threads = 128 rows; thread computes 4 rows x 4 cols fp32, stores
// fp16 pairs (uint2 = 4 halves). W1 in LDS as float4.
__global__ __launch_bounds__(256) void gemm1(const float* __restrict__ x,
                                             const float* __restrict__ W1,
                                             const float* __restrict__ inv,
                                             __half* __restrict__ xwh, int N) {
    __shared__ float4 sW4[IN_DIM * 8];   // 16 KB  (W1 as [128][8] float4)
    for (int i = threadIdx.x; i < IN_DIM * 8; i += 256)
        sW4[i] = ((const float4*)W1)[i];
    __syncthreads();

    int rq = threadIdx.x >> 3;           // 0..31 -> 4-row group
    int cq = threadIdx.x & 7;            // col quad (4 cols)
    int r0 = blockIdx.x * 128 + rq * 4;
    const float4* x4 = (const float4*)x; // x as [N][32] float4
    const float4 z4 = make_float4(0.f, 0.f, 0.f, 0.f);

    float4 acc[4];
#pragma unroll
    for (int i = 0; i < 4; ++i) acc[i] = z4;

    for (int k4 = 0; k4 < IN_DIM / 4; ++k4) {   // 32 iterations
        float4 xa[4];
#pragma unroll
        for (int i = 0; i < 4; ++i) {
            int r = r0 + i;
            xa[i] = (r < N) ? x4[(size_t)r * 32 + k4] : z4;
        }
#pragma unroll
        for (int kk = 0; kk < 4; ++kk) {
            float4 w = sW4[(k4 * 4 + kk) * 8 + cq];
#pragma unroll
            for (int i = 0; i < 4; ++i) {
                float xs = (kk == 0) ? xa[i].x : (kk == 1) ? xa[i].y
                         : (kk == 2) ? xa[i].z : xa[i].w;
                acc[i].x += xs * w.x;
                acc[i].y += xs * w.y;
                acc[i].z += xs * w.z;
                acc[i].w += xs * w.w;
            }
        }
    }

#pragma unroll
    for (int i = 0; i < 4; ++i) {
        int r = r0 + i;
        if (r <= N) {                         // row N: acc==0, scale 0
            float sc = (r < N) ? inv[r] : 0.f;
            __half2 p0 = __floats2half2_rn(acc[i].x * sc, acc[i].y * sc);
            __half2 p1 = __floats2half2_rn(acc[i].z * sc, acc[i].w * sc);
            uint2 u;
            u.x = *(unsigned int*)&p0;
            u.y = *(unsigned int*)&p1;
            ((uint2*)xwh)[(size_t)r * 8 + cq] = u;
        }
    }
}

// ---------------------------------------------------------------------------
// Layer-1 aggregate + fused gemm2: one 64-lane wave per node, BARRIER-FREE.
// lane = eg*8 + r: edge slot eg (0..7), channel quad r (0..7, 4 halves=8B).
// sW2 duplicated per wave; sAgg per-wave -> all LDS traffic wave-local, so
// the block barrier is replaced by s_waitcnt lgkmcnt(0). srcs preloads are
// pre-scaled to byte offsets (sv<<6). Phase-split vals[8]; zero row at N.
__global__ __launch_bounds__(256) void agg1_k(const int* __restrict__ rowStart,
                                              const int* __restrict__ cnt,
                                              const int* __restrict__ srcs,
                                              const float* __restrict__ inv,
                                              const __half* __restrict__ xwh,
                                              const float* __restrict__ b1,
                                              const float* __restrict__ W2,
                                              __half* __restrict__ hwh, int N) {
    __shared__ float sW2[4][HID1 * HID2];   // per-wave copies, 8 KB
    __shared__ float sAgg[4][HID1];         // per-wave, 512 B

    int w    = threadIdx.x >> 6;         // wave in block
    int lane = threadIdx.x & 63;
    // per-wave W2 copy (wave-local LDS only)
    for (int i = lane; i < HID1 * HID2 / 4; i += 64)
        ((float4*)sW2[w])[i] = ((const float4*)W2)[i];

    int node = blockIdx.x * 4 + w;
    int nr   = (node < N) ? node : 0;    // safe read index
    int start = rowStart[nr];
    int len   = (node < N) ? cnt[nr] : 0;
    float invn = (node < N) ? inv[nr] : 0.f;   // node==N pad -> 0 output
    int eg = lane >> 3;                  // edge slot
    int r  = lane & 7;                   // channel quad
    const char* base = (const char*)xwh;
    int roff = r * 8;

    int svb = ((lane < len) ? srcs[start + lane] : N) << 6;  // row BYTE offset
    uint2 selfv = *(const uint2*)(base + ((size_t)nr << 6) + roff);

    // phase 1: issue all group gathers (static indices -> registers)
    uint2 vals[8];
#pragma unroll
    for (int g = 0; g < 8; ++g) {
        int jb = g * 8;
        if (jb < len) {                                  // wave-uniform branch
            int off = __shfl(svb, jb + eg, 64);          // pad slots -> row N
            vals[g] = *(const uint2*)(base + off + roff);
        }
    }
    // phase 2: accumulate
    float4 acc = make_float4(0.f, 0.f, 0.f, 0.f);
    if (eg == 0) h8acc(acc, selfv);
#pragma unroll
    for (int g = 0; g < 8; ++g)
        if (g * 8 < len) h8acc(acc, vals[g]);

    for (int j = 64 + eg; j < len; j += 8)               // ultra-rare tail
        h8acc(acc, *(const uint2*)(base + ((size_t)srcs[start + j] << 6) + roff));

#pragma unroll
    for (int off = 32; off >= 8; off >>= 1) {            // reduce over eg
        acc.x += __shfl_down(acc.x, off, 64);
        acc.y += __shfl_down(acc.y, off, 64);
        acc.z += __shfl_down(acc.z, off, 64);
        acc.w += __shfl_down(acc.w, off, 64);
    }
    if (lane < 8) {                                      // lanes 0..7: r=lane
        float4 bb = ((const float4*)b1)[lane];
        float4 o;
        o.x = fmaxf(bb.x + invn * acc.x, 0.f);
        o.y = fmaxf(bb.y + invn * acc.y, 0.f);
        o.z = fmaxf(bb.z + invn * acc.z, 0.f);
        o.w = fmaxf(bb.w + invn * acc.w, 0.f);
        ((float4*)&sAgg[w][0])[lane] = o;
    }
    // wave-local LDS RAW: wait for this wave's ds_writes, no block barrier
    asm volatile("s_waitcnt lgkmcnt(0)" ::: "memory");

    // fused gemm2: 16 lanes per wave, y[o] = sum_c sAgg[w][c] * W2[c][o]
    if (lane < HID2 && node <= N) {
        float y = 0.f;
#pragma unroll
        for (int cc = 0; cc < HID1; ++cc)
            y += sAgg[w][cc] * sW2[w][cc * HID2 + lane];
        hwh[(size_t)node * HID2 + lane] = __float2half_rn(y * invn);  // row N = 0
    }
}

// Layer-2 aggregate: TWO nodes per wave (half-wave each). Within a half:
// eg = edge slot (0..7), q = channel quad (0..3, 8 B). Two preload registers
// cover 64 slots; groups are wave-uniform via lenmax (short half gathers the
// zero pad row). 50K waves; gather instructions halved vs 1-node/wave.
__global__ __launch_bounds__(256) void agg2_k(const int* __restrict__ rowStart,
                                              const int* __restrict__ cnt,
                                              const int* __restrict__ srcs,
                                              const float* __restrict__ inv,
                                              const __half* __restrict__ hwh,
                                              const float* __restrict__ b2,
                                              float* __restrict__ out, int N) {
    int wpair = (blockIdx.x * blockDim.x + threadIdx.x) >> 6;
    if (wpair * 2 >= N) return;
    int lane = threadIdx.x & 63;
    int half = lane >> 5;          // which node of the pair
    int l32  = lane & 31;
    int n    = wpair * 2 + half;
    bool live = (n < N);
    int nr   = live ? n : 0;
    int start = rowStart[nr];
    int len   = live ? cnt[nr] : 0;
    float invn = live ? inv[nr] : 0.f;
    int eg = l32 >> 2;             // edge slot 0..7
    int q  = l32 & 3;              // channel quad
    const char* base = (const char*)hwh;
    int roff = q * 8;

    // preload up to 64 srcs per half as byte offsets (pad -> row N)
    int svbA = ((l32 < len)      ? srcs[start + l32]      : N) << 5;  // slots 0..31
    int svbB = ((l32 + 32 < len) ? srcs[start + 32 + l32] : N) << 5;  // slots 32..63
    uint2 selfv = *(const uint2*)(base + ((size_t)nr << 5) + roff);

    int lenmax = max(len, __shfl_xor(len, 32, 64));      // wave-uniform bound

    uint2 vals[8];
#pragma unroll
    for (int g = 0; g < 8; ++g) {
        int jb = g * 8;
        if (jb < lenmax) {                               // wave-uniform branch
            // slot j = jb + eg; register choice static per g (jb<32 -> A)
            int off = __shfl((jb < 32) ? svbA : svbB,
                             (half << 5) + ((jb + eg) & 31), 64);
            vals[g] = *(const uint2*)(base + off + roff);
        }
    }
    float4 acc = make_float4(0.f, 0.f, 0.f, 0.f);
    if (eg == 0) h8acc(acc, selfv);                      // self term (pad: zero row)
#pragma unroll
    for (int g = 0; g < 8; ++g)
        if (g * 8 < lenmax) h8acc(acc, vals[g]);         // pad slots add zero row

    for (int j = 64 + eg; j < len; j += 8)               // ultra-rare tail
        h8acc(acc, *(const uint2*)(base + ((size_t)srcs[start + j] << 5) + roff));

#pragma unroll
    for (int off = 16; off >= 4; off >>= 1) {            // reduce over eg (in half)
        acc.x += __shfl_down(acc.x, off, 64);
        acc.y += __shfl_down(acc.y, off, 64);
        acc.z += __shfl_down(acc.z, off, 64);
        acc.w += __shfl_down(acc.w, off, 64);
    }
    if (l32 < 4 && live) {                               // q = l32
        float4 bb = ((const float4*)b2)[l32];
        float4 o;
        o.x = bb.x + invn * acc.x;
        o.y = bb.y + invn * acc.y;
        o.z = bb.z + invn * acc.z;
        o.w = bb.w + invn * acc.w;
        ((float4*)out)[(size_t)n * 4 + l32] = o;
    }
}

// ---------------------------------------------------------------------------
extern "C" void kernel_launch(void* const* d_in, const int* in_sizes, int n_in,
                              void* d_out, int out_size, void* d_ws, size_t ws_size,
                              hipStream_t stream) {
    const float* x  = (const float*)d_in[0];
    const float* W1 = (const float*)d_in[1];
    const float* b1 = (const float*)d_in[2];
    const float* W2 = (const float*)d_in[3];
    const float* b2 = (const float*)d_in[4];
    const int*  e32 = (const int*)d_in[5];
    float* out = (float*)d_out;

    const int N = in_sizes[0] / IN_DIM;   // 100000
    const int E = in_sizes[5] / 2;        // 3200000
    const int Npad = ((N + 63) / 64) * 64;
    const int Epad = ((E + 63) / 64) * 64;
    const int NB   = (N + (1 << BSHIFT) - 1) >> BSHIFT;   // 782 buckets of 128

    // workspace layout (byte-based)
    char* ws = (char*)d_ws;
    int*   flag         = (int*)ws;                       // 1
    int*   total        = (int*)(ws + 64);                // 1
    int*   bucketCursor = (int*)(ws + 256);               // NB (<=1024)
    int*   cnt      = bucketCursor + 1088;                // N
    int*   rowStart = cnt + Npad;                         // N
    float* inv      = (float*)(rowStart + Npad);          // N
    int*   srcs     = (int*)(inv + Npad);                 // E
    // part (NB*SLABCAP u32 = 14.1MB) aliases xwh ((N+1)*32 halves = 6.4MB):
    // part dead before gemm1 writes xwh. hwh after the part region.
    size_t slabBytes = (size_t)NB * SLABCAP * 4;
    unsigned int* part = (unsigned int*)(srcs + Epad);
    __half* xwh = (__half*)part;
    __half* hwh = (__half*)((char*)part + slabBytes);     // (N+1)*16 halves

    init_cursors<<<(NB + 255) / 256, 256, 0, stream>>>(e32, flag, total,
                                                       bucketCursor, NB);
    partition_edges<<<(E + P2T - 1) / P2T, 1024, 0, stream>>>(
        e32, flag, bucketCursor, part, E, NB);
    build_rows<<<NB, 256, 0, stream>>>(part, bucketCursor, total,
                                       rowStart, cnt, inv, srcs, N);

    gemm1<<<(N + 1 + 127) / 128, 256, 0, stream>>>(x, W1, inv, xwh, N);
    agg1_k<<<(N + 1 + 3) / 4, 256, 0, stream>>>(rowStart, cnt, srcs, inv, xwh,
                                                b1, W2, hwh, N);
    int pairs = (N + 1) / 2;   // 2 nodes per wave
    agg2_k<<<(pairs + 3) / 4, 256, 0, stream>>>(rowStart, cnt, srcs, inv, hwh,
                                                b2, out, N);
}

// Round 16
// 250.140 us; speedup vs baseline: 1.1634x; 1.0622x over previous
//
#include <hip/hip_runtime.h>
#include <hip/hip_fp16.h>

// GCN 2-layer: out = (Â relu(Â (x@W1) + b1)) @ W2 + b2,  Â = D^-1/2 (A+I) D^-1/2
// N=100000, E=3200000, dims 128 -> 32 -> 16, fp32 in/out.
// Round 18: agg1 packs 2 NODES PER WAVE (the r16 agg2 pattern, +12us there).
// agg1 was pinned at ~56.5us across six variants: per-wave fixed overhead at
// 100K waves (preamble chain, srcs preload, sW2 copy, 3 reduce rounds,
// epilogue), NOT L3 service (r12: time flat when FETCH 100->35MB). Half-wave
// per node (eg 0..3 x r 0..7); 50K waves; reduce 3->2 rounds; sW2 copies
// halved. Two-phase gather keeps VGPR low: vals[8] slots 0-31, reuse for
// 32-63, phase B only when lenmax>32 (wave-uniform via shfl_xor(len,32);
// short half gathers the zero pad row). Fused gemm2: 16 lanes per half.
// Frozen from r17 (265.7us best): reg-staged big-tile partition, LDS
// build_rows, reg-blocked fp16 gemm1, 2-node/wave agg2.

#define IN_DIM 128
#define HID1 32
#define HID2 16

#define BSHIFT 7                 // 128 nodes per bucket
#define MAXNB 1024               // supports N <= 131072 (src < 2^17 packing)
#define SLABCAP 4736             // slab capacity per bucket (mean 4096 + 10 sigma)
#define P2T 16384                // edges per workgroup in partition pass
#define P2_PER_THREAD 16         // 16 edges x 1024 threads = 16384

__device__ __forceinline__ void load_edge(const int* __restrict__ e32, int is64,
                                          long e, long E, int& s, int& d) {
    if (is64) { s = e32[2 * e];  d = e32[2 * E + 2 * e]; }
    else      { s = e32[e];      d = e32[E + e]; }
}

__device__ __forceinline__ void h8acc(float4& acc, uint2 u) {
    __half2 a = *(__half2*)&u.x, b = *(__half2*)&u.y;
    float2 fa = __half22float2(a), fb = __half22float2(b);
    acc.x += fa.x; acc.y += fa.y; acc.z += fb.x; acc.w += fb.y;
}

// ---------------------------------------------------------------------------
// init cursors + total + edge dtype probe
__global__ void init_cursors(const int* __restrict__ e32, int* __restrict__ flag,
                             int* __restrict__ total,
                             int* __restrict__ bucketCursor, int NB) {
    int i = blockIdx.x * blockDim.x + threadIdx.x;
    if (i < NB) bucketCursor[i] = i * SLABCAP;
    if (blockIdx.x == 0 && threadIdx.x == 0) {
        *total = 0;
        int is64 = 1;
        for (int k = 0; k < 64; ++k)
            if (e32[2 * k + 1] != 0) { is64 = 0; break; }
        *flag = is64;
    }
}

// Partition edges into per-bucket slabs as packed u32 (src | dstLocal<<17).
// Register-staged big tile: 16 edges/thread loaded independently (latency
// batched), LDS histogram, one chunk reservation per bucket, placement.
__global__ __launch_bounds__(1024) void partition_edges(const int* __restrict__ e32,
                                                        const int* __restrict__ flag,
                                                        int* __restrict__ bucketCursor,
                                                        unsigned int* __restrict__ part,
                                                        int E, int NB) {
    __shared__ int lbase[MAXNB];   // histogram, then global-base cursor
    for (int i = threadIdx.x; i < NB; i += 1024) lbase[i] = 0;
    __syncthreads();
    int is64 = *flag;
    long e0 = (long)blockIdx.x * P2T;
    unsigned int v[P2_PER_THREAD];
    int bb[P2_PER_THREAD];
#pragma unroll
    for (int i = 0; i < P2_PER_THREAD; ++i) {
        long e = e0 + threadIdx.x + i * 1024;
        if (e < E) {
            int s, d;
            load_edge(e32, is64, e, E, s, d);
            bb[i] = d >> BSHIFT;
            v[i] = (unsigned int)s | ((unsigned int)(d & ((1 << BSHIFT) - 1)) << 17);
            atomicAdd(&lbase[bb[i]], 1);
        } else {
            bb[i] = -1;
        }
    }
    __syncthreads();
    // reserve one contiguous chunk per non-empty bucket (cursor at slab base)
    for (int b = threadIdx.x; b < NB; b += 1024) {
        int c = lbase[b];
        lbase[b] = c ? atomicAdd(&bucketCursor[b], c) : 0;
    }
    __syncthreads();
#pragma unroll
    for (int i = 0; i < P2_PER_THREAD; ++i) {
        if (bb[i] >= 0) {
            int pos = atomicAdd(&lbase[bb[i]], 1);
            if (pos < (bb[i] + 1) * SLABCAP)   // overflow guard (P ~ 1e-20)
                part[pos] = v[i];
        }
    }
}

// P3: one WG (256 thr) per 128-node bucket. Slab staged in LDS once; count,
// scan (128 wide), scatter srcs into a region allocated by one global
// atomicAdd. Emits rowStart/cnt/inv.
__global__ __launch_bounds__(256) void build_rows(const unsigned int* __restrict__ part,
                                                  const int* __restrict__ bucketCursor,
                                                  int* __restrict__ total,
                                                  int* __restrict__ rowStart,
                                                  int* __restrict__ cnt,
                                                  float* __restrict__ inv,
                                                  int* __restrict__ srcs, int N) {
    __shared__ unsigned int sSlab[SLABCAP];   // 18.5 KB
    __shared__ int lc[128];
    __shared__ int lofs[128];
    __shared__ int wsum[2];
    __shared__ int sGbase;
    int b = blockIdx.x;
    int sbeg = b * SLABCAP;
    int size = bucketCursor[b] - sbeg;
    if (size > SLABCAP) size = SLABCAP;
    int tid = threadIdx.x;
    if (tid < 128) lc[tid] = 0;
    __syncthreads();
    for (int i = tid; i < size; i += 256) {      // single global read of slab
        unsigned int v = part[sbeg + i];
        sSlab[i] = v;
        atomicAdd(&lc[v >> 17], 1);
    }
    if (tid == 0) sGbase = atomicAdd(total, size);   // region alloc (any order)
    __syncthreads();
    if (tid < 128) {
        int gbase = sGbase;
        int c = lc[tid];
        int s = c;
#pragma unroll
        for (int off = 1; off < 64; off <<= 1) {
            int t = __shfl_up(s, off, 64);
            if ((tid & 63) >= off) s += t;
        }
        if ((tid & 63) == 63) wsum[tid >> 6] = s;
        __syncthreads();
        int wb = (tid >= 64) ? wsum[0] : 0;
        int gstart = gbase + wb + s - c;   // exclusive scan + region base
        int n = (b << BSHIFT) + tid;
        if (n < N) {
            rowStart[n] = gstart;
            cnt[n] = c;
            inv[n] = rsqrtf((float)(c + 1));
        }
        lofs[tid] = gstart;
    } else {
        __syncthreads();
    }
    __syncthreads();
    for (int i = tid; i < size; i += 256) {
        unsigned int v = sSlab[i];
        int pos = atomicAdd(&lofs[v >> 17], 1);
        srcs[pos] = (int)(v & 0x1FFFF);
    }
}

// ---------------------------------------------------------------------------
// xwh = fp16( (x @ W1) * inv[row] ), rows 0..N inclusive (row N = zero pad).
// Block 256 threads = 128 rows; thread computes 4 rows x 4 cols fp32, stores
// fp16 pairs (uint2 = 4 halves). W1 in LDS as float4.
__global__ __launch_bounds__(256) void gemm1(const float* __restrict__ x,
                                             const float* __restrict__ W1,
                                             const float* __restrict__ inv,
                                             __half* __restrict__ xwh, int N) {
    __shared__ float4 sW4[IN_DIM * 8];   // 16 KB  (W1 as [128][8] float4)
    for (int i = threadIdx.x; i < IN_DIM * 8; i += 256)
        sW4[i] = ((const float4*)W1)[i];
    __syncthreads();

    int rq = threadIdx.x >> 3;           // 0..31 -> 4-row group
    int cq = threadIdx.x & 7;            // col quad (4 cols)
    int r0 = blockIdx.x * 128 + rq * 4;
    const float4* x4 = (const float4*)x; // x as [N][32] float4
    const float4 z4 = make_float4(0.f, 0.f, 0.f, 0.f);

    float4 acc[4];
#pragma unroll
    for (int i = 0; i < 4; ++i) acc[i] = z4;

    for (int k4 = 0; k4 < IN_DIM / 4; ++k4) {   // 32 iterations
        float4 xa[4];
#pragma unroll
        for (int i = 0; i < 4; ++i) {
            int r = r0 + i;
            xa[i] = (r < N) ? x4[(size_t)r * 32 + k4] : z4;
        }
#pragma unroll
        for (int kk = 0; kk < 4; ++kk) {
            float4 w = sW4[(k4 * 4 + kk) * 8 + cq];
#pragma unroll
            for (int i = 0; i < 4; ++i) {
                float xs = (kk == 0) ? xa[i].x : (kk == 1) ? xa[i].y
                         : (kk == 2) ? xa[i].z : xa[i].w;
                acc[i].x += xs * w.x;
                acc[i].y += xs * w.y;
                acc[i].z += xs * w.z;
                acc[i].w += xs * w.w;
            }
        }
    }

#pragma unroll
    for (int i = 0; i < 4; ++i) {
        int r = r0 + i;
        if (r <= N) {                         // row N: acc==0, scale 0
            float sc = (r < N) ? inv[r] : 0.f;
            __half2 p0 = __floats2half2_rn(acc[i].x * sc, acc[i].y * sc);
            __half2 p1 = __floats2half2_rn(acc[i].z * sc, acc[i].w * sc);
            uint2 u;
            u.x = *(unsigned int*)&p0;
            u.y = *(unsigned int*)&p1;
            ((uint2*)xwh)[(size_t)r * 8 + cq] = u;
        }
    }
}

// ---------------------------------------------------------------------------
// Layer-1 aggregate + fused gemm2: TWO nodes per wave (half-wave each),
// BARRIER-FREE. Within a half: eg = edge slot (0..3), r = channel quad
// (0..7, 8 B -> full 64B row per 8 lanes). Two preload registers cover 64
// slots; phase A gathers slots 0-31 (vals[8]), phase B (register-reused)
// slots 32-63 only when lenmax>32 (wave-uniform via shfl_xor(len,32); short
// half gathers the zero pad row). Reduce: 2 rounds. sW2 per wave; all LDS
// wave-local -> s_waitcnt lgkmcnt(0) instead of __syncthreads. 50K waves.
__global__ __launch_bounds__(256) void agg1_k(const int* __restrict__ rowStart,
                                              const int* __restrict__ cnt,
                                              const int* __restrict__ srcs,
                                              const float* __restrict__ inv,
                                              const __half* __restrict__ xwh,
                                              const float* __restrict__ b1,
                                              const float* __restrict__ W2,
                                              __half* __restrict__ hwh, int N) {
    __shared__ float sW2[4][HID1 * HID2];   // per-wave copies, 8 KB
    __shared__ float sAgg[4][2][HID1];      // per-wave per-half, 1 KB

    int w    = threadIdx.x >> 6;         // wave in block
    int lane = threadIdx.x & 63;
    // per-wave W2 copy (wave-local LDS only)
    for (int i = lane; i < HID1 * HID2 / 4; i += 64)
        ((float4*)sW2[w])[i] = ((const float4*)W2)[i];

    int wpair = blockIdx.x * 4 + w;
    int half  = lane >> 5;               // which node of the pair
    int l32   = lane & 31;
    int node  = wpair * 2 + half;        // 0 .. N (pad row N included)
    bool haveRow = (node < N);
    int nr    = haveRow ? node : 0;      // safe read index
    int start = rowStart[nr];
    int len   = haveRow ? cnt[nr] : 0;
    float invn = haveRow ? inv[nr] : 0.f;   // pad/overflow -> 0 output
    int eg = l32 >> 3;                   // edge slot 0..3
    int r  = l32 & 7;                    // channel quad
    const char* base = (const char*)xwh;
    int roff = r * 8;

    // preload up to 64 srcs per half as byte offsets (pad -> row N = zeros)
    int svbA = ((l32 < len)      ? srcs[start + l32]      : N) << 6;  // slots 0..31
    int svbB = ((l32 + 32 < len) ? srcs[start + 32 + l32] : N) << 6;  // slots 32..63
    uint2 selfv = *(const uint2*)(base + ((size_t)nr << 6) + roff);

    int lenmax = max(len, __shfl_xor(len, 32, 64));      // wave-uniform bound

    float4 acc = make_float4(0.f, 0.f, 0.f, 0.f);

    // phase A: slots 0..31 (8 groups x 4 edges), all loads issued before use
    {
        uint2 vals[8];
#pragma unroll
        for (int g = 0; g < 8; ++g) {
            int jb = g * 4;
            if (jb < lenmax) {                           // wave-uniform branch
                int off = __shfl(svbA, (half << 5) + (jb + eg), 64);
                vals[g] = *(const uint2*)(base + off + roff);
            }
        }
        if (eg == 0) h8acc(acc, selfv);                  // self (pad: row N = 0... nr junk ok, invn=0)
#pragma unroll
        for (int g = 0; g < 8; ++g)
            if (g * 4 < lenmax) h8acc(acc, vals[g]);     // pad slots add zero row
    }
    // phase B: slots 32..63, entered only when some half exceeds 32
    if (lenmax > 32) {
        uint2 vals[8];
#pragma unroll
        for (int g = 0; g < 8; ++g) {
            int jb = 32 + g * 4;
            if (jb < lenmax) {
                int off = __shfl(svbB, (half << 5) + (g * 4 + eg), 64);
                vals[g] = *(const uint2*)(base + off + roff);
            }
        }
#pragma unroll
        for (int g = 0; g < 8; ++g)
            if (32 + g * 4 < lenmax) h8acc(acc, vals[g]);
    }
    for (int j = 64 + eg; j < len; j += 4)               // ultra-rare tail
        h8acc(acc, *(const uint2*)(base + ((size_t)srcs[start + j] << 6) + roff));

    // reduce over eg within half: l32 strides of 8 (2 rounds)
#pragma unroll
    for (int off = 16; off >= 8; off >>= 1) {
        acc.x += __shfl_down(acc.x, off, 64);
        acc.y += __shfl_down(acc.y, off, 64);
        acc.z += __shfl_down(acc.z, off, 64);
        acc.w += __shfl_down(acc.w, off, 64);
    }
    if (l32 < 8) {                                       // l32 = r
        float4 bb = ((const float4*)b1)[l32];
        float4 o;
        o.x = fmaxf(bb.x + invn * acc.x, 0.f);
        o.y = fmaxf(bb.y + invn * acc.y, 0.f);
        o.z = fmaxf(bb.z + invn * acc.z, 0.f);
        o.w = fmaxf(bb.w + invn * acc.w, 0.f);
        ((float4*)&sAgg[w][half][0])[l32] = o;
    }
    // wave-local LDS RAW: wait for this wave's ds_writes, no block barrier
    asm volatile("s_waitcnt lgkmcnt(0)" ::: "memory");

    // fused gemm2: 16 lanes per half, y[o] = sum_c sAgg[w][half][c]*W2[c][o]
    if (l32 < HID2 && node <= N) {
        float y = 0.f;
#pragma unroll
        for (int cc = 0; cc < HID1; ++cc)
            y += sAgg[w][half][cc] * sW2[w][cc * HID2 + l32];
        hwh[(size_t)node * HID2 + l32] = __float2half_rn(y * invn);  // row N = 0
    }
}

// Layer-2 aggregate: TWO nodes per wave (half-wave each). Within a half:
// eg = edge slot (0..7), q = channel quad (0..3, 8 B). Two preload registers
// cover 64 slots; groups are wave-uniform via lenmax (short half gathers the
// zero pad row). 50K waves; gather instructions halved vs 1-node/wave.
__global__ __launch_bounds__(256) void agg2_k(const int* __restrict__ rowStart,
                                              const int* __restrict__ cnt,
                                              const int* __restrict__ srcs,
                                              const float* __restrict__ inv,
                                              const __half* __restrict__ hwh,
                                              const float* __restrict__ b2,
                                              float* __restrict__ out, int N) {
    int wpair = (blockIdx.x * blockDim.x + threadIdx.x) >> 6;
    if (wpair * 2 >= N) return;
    int lane = threadIdx.x & 63;
    int half = lane >> 5;          // which node of the pair
    int l32  = lane & 31;
    int n    = wpair * 2 + half;
    bool live = (n < N);
    int nr   = live ? n : 0;
    int start = rowStart[nr];
    int len   = live ? cnt[nr] : 0;
    float invn = live ? inv[nr] : 0.f;
    int eg = l32 >> 2;             // edge slot 0..7
    int q  = l32 & 3;              // channel quad
    const char* base = (const char*)hwh;
    int roff = q * 8;

    // preload up to 64 srcs per half as byte offsets (pad -> row N)
    int svbA = ((l32 < len)      ? srcs[start + l32]      : N) << 5;  // slots 0..31
    int svbB = ((l32 + 32 < len) ? srcs[start + 32 + l32] : N) << 5;  // slots 32..63
    uint2 selfv = *(const uint2*)(base + ((size_t)nr << 5) + roff);

    int lenmax = max(len, __shfl_xor(len, 32, 64));      // wave-uniform bound

    uint2 vals[8];
#pragma unroll
    for (int g = 0; g < 8; ++g) {
        int jb = g * 8;
        if (jb < lenmax) {                               // wave-uniform branch
            // slot j = jb + eg; register choice static per g (jb<32 -> A)
            int off = __shfl((jb < 32) ? svbA : svbB,
                             (half << 5) + ((jb + eg) & 31), 64);
            vals[g] = *(const uint2*)(base + off + roff);
        }
    }
    float4 acc = make_float4(0.f, 0.f, 0.f, 0.f);
    if (eg == 0) h8acc(acc, selfv);                      // self term (pad: zero row)
#pragma unroll
    for (int g = 0; g < 8; ++g)
        if (g * 8 < lenmax) h8acc(acc, vals[g]);         // pad slots add zero row

    for (int j = 64 + eg; j < len; j += 8)               // ultra-rare tail
        h8acc(acc, *(const uint2*)(base + ((size_t)srcs[start + j] << 5) + roff));

#pragma unroll
    for (int off = 16; off >= 4; off >>= 1) {            // reduce over eg (in half)
        acc.x += __shfl_down(acc.x, off, 64);
        acc.y += __shfl_down(acc.y, off, 64);
        acc.z += __shfl_down(acc.z, off, 64);
        acc.w += __shfl_down(acc.w, off, 64);
    }
    if (l32 < 4 && live) {                               // q = l32
        float4 bb = ((const float4*)b2)[l32];
        float4 o;
        o.x = bb.x + invn * acc.x;
        o.y = bb.y + invn * acc.y;
        o.z = bb.z + invn * acc.z;
        o.w = bb.w + invn * acc.w;
        ((float4*)out)[(size_t)n * 4 + l32] = o;
    }
}

// ---------------------------------------------------------------------------
extern "C" void kernel_launch(void* const* d_in, const int* in_sizes, int n_in,
                              void* d_out, int out_size, void* d_ws, size_t ws_size,
                              hipStream_t stream) {
    const float* x  = (const float*)d_in[0];
    const float* W1 = (const float*)d_in[1];
    const float* b1 = (const float*)d_in[2];
    const float* W2 = (const float*)d_in[3];
    const float* b2 = (const float*)d_in[4];
    const int*  e32 = (const int*)d_in[5];
    float* out = (float*)d_out;

    const int N = in_sizes[0] / IN_DIM;   // 100000
    const int E = in_sizes[5] / 2;        // 3200000
    const int Npad = ((N + 63) / 64) * 64;
    const int Epad = ((E + 63) / 64) * 64;
    const int NB   = (N + (1 << BSHIFT) - 1) >> BSHIFT;   // 782 buckets of 128

    // workspace layout (byte-based)
    char* ws = (char*)d_ws;
    int*   flag         = (int*)ws;                       // 1
    int*   total        = (int*)(ws + 64);                // 1
    int*   bucketCursor = (int*)(ws + 256);               // NB (<=1024)
    int*   cnt      = bucketCursor + 1088;                // N
    int*   rowStart = cnt + Npad;                         // N
    float* inv      = (float*)(rowStart + Npad);          // N
    int*   srcs     = (int*)(inv + Npad);                 // E
    // part (NB*SLABCAP u32 = 14.1MB) aliases xwh ((N+1)*32 halves = 6.4MB):
    // part dead before gemm1 writes xwh. hwh after the part region.
    size_t slabBytes = (size_t)NB * SLABCAP * 4;
    unsigned int* part = (unsigned int*)(srcs + Epad);
    __half* xwh = (__half*)part;
    __half* hwh = (__half*)((char*)part + slabBytes);     // (N+1)*16 halves

    init_cursors<<<(NB + 255) / 256, 256, 0, stream>>>(e32, flag, total,
                                                       bucketCursor, NB);
    partition_edges<<<(E + P2T - 1) / P2T, 1024, 0, stream>>>(
        e32, flag, bucketCursor, part, E, NB);
    build_rows<<<NB, 256, 0, stream>>>(part, bucketCursor, total,
                                       rowStart, cnt, inv, srcs, N);

    gemm1<<<(N + 1 + 127) / 128, 256, 0, stream>>>(x, W1, inv, xwh, N);
    int pairs1 = (N + 2) / 2;   // 2 nodes per wave, incl. pad row N
    agg1_k<<<(pairs1 + 3) / 4, 256, 0, stream>>>(rowStart, cnt, srcs, inv, xwh,
                                                 b1, W2, hwh, N);
    int pairs = (N + 1) / 2;    // 2 nodes per wave
    agg2_k<<<(pairs + 3) / 4, 256, 0, stream>>>(rowStart, cnt, srcs, inv, hwh,
                                                b2, out, N);
}